// Round 2
// baseline (2195.753 us; speedup 1.0000x reference)
//
#include <hip/hip_runtime.h>
#include <hip/hip_bf16.h>
#include <stdint.h>

#define NN 131072
#define NE 262144
#define DD 300
#define DP 320
#define D2 600
#define D2P 640
#define NL 5
#define BN_EPS 1e-5f

typedef __attribute__((ext_vector_type(8))) _Float16 f16x8;
typedef __attribute__((ext_vector_type(4))) float f32x4;
typedef __attribute__((ext_vector_type(4))) unsigned int uint4v;

static __device__ __forceinline__ float h2f(unsigned short u) {
    union { unsigned short u; _Float16 h; } c; c.u = u; return (float)c.h;
}
static __device__ __forceinline__ unsigned short f2h(float f) {
    union { unsigned short u; _Float16 h; } c; c.h = (_Float16)f; return c.u;
}

// ---------------- prep kernels ----------------

// W1 [L,300,600] fp32 -> W1t [L][640][320] f16 (n-major, k-contig, zero pad)
__global__ void k_w1t(const float* __restrict__ W1, unsigned short* __restrict__ W1t) {
    int idx = blockIdx.x * 256 + threadIdx.x;
    if (idx >= NL * D2P * DP) return;
    int l = idx / (D2P * DP);
    int r = idx % (D2P * DP);
    int n = r / DP, k = r % DP;
    float v = (n < D2 && k < DD) ? W1[(size_t)(l * DD + k) * D2 + n] : 0.f;
    W1t[idx] = f2h(v);
}

// W2 [L,600,300] fp32 -> W2t [L][320][640] f16
__global__ void k_w2t(const float* __restrict__ W2, unsigned short* __restrict__ W2t) {
    int idx = blockIdx.x * 256 + threadIdx.x;
    if (idx >= NL * DP * D2P) return;
    int l = idx / (DP * D2P);
    int r = idx % (DP * D2P);
    int n = r / D2P, k = r % D2P;
    float v = (n < DD && k < D2) ? W2[(size_t)(l * D2 + k) * DD + n] : 0.f;
    W2t[idx] = f2h(v);
}

// edge-embedding combos: eec [L][15][320] f16; combo = bond*3 + dir
__global__ void k_eec(const float* __restrict__ ee1, const float* __restrict__ ee2,
                      unsigned short* __restrict__ eec) {
    int idx = blockIdx.x * 256 + threadIdx.x;
    if (idx >= NL * 15 * DP) return;
    int l = idx / (15 * DP);
    int r = idx % (15 * DP);
    int cb = r / DP, c = r % DP;
    int b = cb / 3, d = cb % 3;
    float v = 0.f;
    if (c < DD) v = ee1[(size_t)(l * 5 + b) * DD + c] + ee2[(size_t)(l * 3 + d) * DD + c];
    eec[idx] = f2h(v);
}

// h0[n][c] = x_emb1[x[n,0]][c] + x_emb2[x[n,1]][c], f16 padded [N][320]
__global__ void k_h0(const int* __restrict__ x, const float* __restrict__ xe1,
                     const float* __restrict__ xe2, unsigned short* __restrict__ h) {
    unsigned int idx = blockIdx.x * 256u + threadIdx.x;
    if (idx >= (unsigned int)NN * DP) return;
    unsigned int n = idx / DP, c = idx % DP;
    float v = 0.f;
    if (c < DD) v = xe1[(size_t)x[2 * n] * DD + c] + xe2[(size_t)x[2 * n + 1] * DD + c];
    h[idx] = f2h(v);
}

__global__ void k_ident(float* __restrict__ sc, float* __restrict__ sh) {
    int t = blockIdx.x * 256 + threadIdx.x;
    if (t < DP) { sc[t] = 1.f; sh[t] = 0.f; }
}

// ---------------- CSR build ----------------

__global__ void k_count(const int* __restrict__ ei, int* __restrict__ counts) {
    int e = blockIdx.x * 256 + threadIdx.x;
    if (e < NE) atomicAdd(&counts[ei[NE + e]], 1);
}

__global__ void k_scan1(const int* __restrict__ counts, int* __restrict__ partial) {
    __shared__ int sm[256];
    int t = threadIdx.x;
    sm[t] = counts[blockIdx.x * 256 + t];
    __syncthreads();
    for (int o = 128; o > 0; o >>= 1) {
        if (t < o) sm[t] += sm[t + o];
        __syncthreads();
    }
    if (t == 0) partial[blockIdx.x] = sm[0];
}

__global__ void k_scan2(const int* __restrict__ partial, int* __restrict__ partial2) {
    __shared__ int sm[512];
    int t = threadIdx.x;
    int v = partial[t];
    sm[t] = v;
    __syncthreads();
    for (int o = 1; o < 512; o <<= 1) {
        int add = (t >= o) ? sm[t - o] : 0;
        __syncthreads();
        sm[t] += add;
        __syncthreads();
    }
    partial2[t] = sm[t] - v;  // exclusive
}

__global__ void k_scan3(const int* __restrict__ counts, const int* __restrict__ partial2,
                        int* __restrict__ row_ptr, int* __restrict__ cursor) {
    __shared__ int sm[256];
    int t = threadIdx.x;
    int i = blockIdx.x * 256 + t;
    int v = counts[i];
    sm[t] = v;
    __syncthreads();
    for (int o = 1; o < 256; o <<= 1) {
        int add = (t >= o) ? sm[t - o] : 0;
        __syncthreads();
        sm[t] += add;
        __syncthreads();
    }
    int excl = partial2[blockIdx.x] + sm[t] - v;
    row_ptr[i] = excl;
    cursor[i] = excl;
    if (i == NN - 1) row_ptr[NN] = excl + v;
}

__global__ void k_fill(const int* __restrict__ ei, const int* __restrict__ ea,
                       int* __restrict__ cursor, int* __restrict__ srcs,
                       int* __restrict__ combos) {
    int e = blockIdx.x * 256 + threadIdx.x;
    if (e >= NE) return;
    int d = ei[NE + e];
    int pos = atomicAdd(&cursor[d], 1);
    srcs[pos] = ei[e];
    combos[pos] = ea[2 * e] * 3 + ea[2 * e + 1];
}

// ---------------- aggregation (pull, CSR) ----------------
// agg[m][c] = sum_e( relu?(sc[c]*h[src_e][c]+sh[c]) + eec[combo_e][c] )
__global__ void k_gather(const unsigned short* __restrict__ h, const float* __restrict__ sc,
                         const float* __restrict__ sh, int relu,
                         const int* __restrict__ row_ptr, const int* __restrict__ srcs,
                         const int* __restrict__ combos, const unsigned short* __restrict__ eec,
                         unsigned short* __restrict__ agg) {
    unsigned int idx = blockIdx.x * 256u + threadIdx.x;  // N*40 chunks of 8 cols
    if (idx >= (unsigned int)NN * 40) return;
    unsigned int m = idx / 40;
    unsigned int j = idx % 40;
    int c0 = j * 8;
    float a[8] = {0, 0, 0, 0, 0, 0, 0, 0};
    float scv[8], shv[8];
#pragma unroll
    for (int i = 0; i < 8; i++) { scv[i] = sc[c0 + i]; shv[i] = sh[c0 + i]; }
    int e0 = row_ptr[m], e1 = row_ptr[m + 1];
    for (int e = e0; e < e1; ++e) {
        int s = srcs[e], cb = combos[e];
        uint4v hv = *(const uint4v*)(h + (size_t)s * DP + c0);
        uint4v ev = *(const uint4v*)(eec + (size_t)cb * DP + c0);
        const unsigned short* hp = (const unsigned short*)&hv;
        const unsigned short* ep = (const unsigned short*)&ev;
#pragma unroll
        for (int i = 0; i < 8; i++) {
            float f = scv[i] * h2f(hp[i]) + shv[i];
            if (relu) f = fmaxf(f, 0.f);
            a[i] += f + h2f(ep[i]);
        }
    }
    unsigned short o[8];
#pragma unroll
    for (int i = 0; i < 8; i++) o[i] = f2h(a[i]);
    *(uint4v*)(agg + (size_t)m * DP + c0) = *(const uint4v*)o;
}

// ---------------- GEMM: C[M,Nout] = affine?(A)[M,K] @ B^T[Nout,K], f16 in/out ----------------
// grid = (Nout/64, M/128), 256 threads (4 waves, 2x2), BK=64
__launch_bounds__(256, 2)
__global__ void k_gemm(const unsigned short* __restrict__ A, int lda, int kIters,
                       const float* __restrict__ aScale, const float* __restrict__ aShift,
                       int aRelu, const unsigned short* __restrict__ B,
                       unsigned short* __restrict__ C, int ldc,
                       float* __restrict__ stats, int statN) {
    __shared__ unsigned short As[128][72];
    __shared__ unsigned short Bs[64][72];
    int tid = threadIdx.x;
    int lane = tid & 63, wid = tid >> 6;
    int wm = wid >> 1, wn = wid & 1;
    int m0 = blockIdx.y * 128;
    int n0 = blockIdx.x * 64;
    int arow = tid >> 3;         // 0..31
    int acol = (tid & 7) * 8;    // 0,8,..,56
    bool affine = (aScale != nullptr);
    f32x4 acc[4][2] = {};

    for (int kt = 0; kt < kIters; ++kt) {
        int k0 = kt * 64;
        float ascv[8], ashv[8];
        if (affine) {
#pragma unroll
            for (int i = 0; i < 8; i++) {
                ascv[i] = aScale[k0 + acol + i];
                ashv[i] = aShift[k0 + acol + i];
            }
        }
        // stage A: 128 rows x 64 cols
#pragma unroll
        for (int r = 0; r < 4; ++r) {
            int row = arow + r * 32;
            uint4v v = *(const uint4v*)(A + (size_t)(m0 + row) * lda + k0 + acol);
            if (affine) {
                unsigned short* pv = (unsigned short*)&v;
#pragma unroll
                for (int i = 0; i < 8; i++) {
                    float f = ascv[i] * h2f(pv[i]) + ashv[i];
                    if (aRelu) f = fmaxf(f, 0.f);
                    pv[i] = f2h(f);
                }
            }
            *(uint4v*)&As[row][acol] = v;
        }
        // stage B: 64 rows x 64 cols
#pragma unroll
        for (int r = 0; r < 2; ++r) {
            int n = arow + r * 32;
            *(uint4v*)&Bs[n][acol] = *(const uint4v*)(B + (size_t)(n0 + n) * lda + k0 + acol);
        }
        __syncthreads();
#pragma unroll
        for (int ks = 0; ks < 2; ++ks) {
            int kb = ks * 32 + (lane >> 4) * 8;
            f16x8 af[4], bg[2];
#pragma unroll
            for (int mf = 0; mf < 4; ++mf)
                af[mf] = *(const f16x8*)&As[wm * 64 + mf * 16 + (lane & 15)][kb];
#pragma unroll
            for (int nf = 0; nf < 2; ++nf)
                bg[nf] = *(const f16x8*)&Bs[wn * 32 + nf * 16 + (lane & 15)][kb];
#pragma unroll
            for (int mf = 0; mf < 4; ++mf)
#pragma unroll
                for (int nf = 0; nf < 2; ++nf)
                    acc[mf][nf] = __builtin_amdgcn_mfma_f32_16x16x32_f16(af[mf], bg[nf], acc[mf][nf], 0, 0, 0);
        }
        __syncthreads();
    }
    // epilogue: store C (f16) + per-column partial stats
#pragma unroll
    for (int nf = 0; nf < 2; ++nf) {
        int col = n0 + wn * 32 + nf * 16 + (lane & 15);
        float s = 0.f, ss = 0.f;
#pragma unroll
        for (int mf = 0; mf < 4; ++mf) {
            int rbase = m0 + wm * 64 + mf * 16 + ((lane >> 4) << 2);
#pragma unroll
            for (int i = 0; i < 4; ++i) {
                float v = acc[mf][nf][i];
                unsigned short hb = f2h(v);
                C[(size_t)(rbase + i) * ldc + col] = hb;
                float vr = h2f(hb);
                s += vr;
                ss += vr * vr;
            }
        }
        s += __shfl_xor(s, 16); s += __shfl_xor(s, 32);
        ss += __shfl_xor(ss, 16); ss += __shfl_xor(ss, 32);
        if (lane < 16) {
            atomicAdd(&stats[col], s);
            atomicAdd(&stats[statN + col], ss);
        }
    }
}

// ---------------- BN scale/shift from stats ----------------
__global__ void k_bnprep(const float* __restrict__ stats, int statN, int realN,
                         const float* __restrict__ g, const float* __restrict__ b,
                         float* __restrict__ sc, float* __restrict__ sh) {
    int n = blockIdx.x * 256 + threadIdx.x;
    if (n >= statN) return;
    if (n < realN) {
        float mu = stats[n] * (1.f / NN);
        float var = stats[statN + n] * (1.f / NN) - mu * mu;
        var = fmaxf(var, 0.f);
        float rs = rsqrtf(var + BN_EPS);
        float scv = g[n] * rs;
        sc[n] = scv;
        sh[n] = b[n] - mu * scv;
    } else {
        sc[n] = 0.f;
        sh[n] = 0.f;
    }
}

// ---------------- final output: out[n,d] = sc[d]*u2[n,d]+sh[d], fp32 ----------------
__global__ void k_out(const unsigned short* __restrict__ u2, const float* __restrict__ sc,
                      const float* __restrict__ sh, float* __restrict__ out) {
    unsigned int idx = blockIdx.x * 256u + threadIdx.x;
    if (idx >= (unsigned int)NN * DD) return;
    unsigned int n = idx / DD, d = idx % DD;
    out[idx] = sc[d] * h2f(u2[(size_t)n * DP + d]) + sh[d];
}

extern "C" void kernel_launch(void* const* d_in, const int* in_sizes, int n_in,
                              void* d_out, int out_size, void* d_ws, size_t ws_size,
                              hipStream_t stream) {
    const int* x = (const int*)d_in[0];
    const int* ei = (const int*)d_in[1];
    const int* ea = (const int*)d_in[2];
    const float* xe1 = (const float*)d_in[3];
    const float* xe2 = (const float*)d_in[4];
    const float* ee1 = (const float*)d_in[5];
    const float* ee2 = (const float*)d_in[6];
    const float* W1 = (const float*)d_in[7];
    const float* bn1g = (const float*)d_in[9];
    const float* bn1b = (const float*)d_in[10];
    const float* W2 = (const float*)d_in[11];
    const float* bng = (const float*)d_in[13];
    const float* bnb = (const float*)d_in[14];
    float* out = (float*)d_out;

    char* ws = (char*)d_ws;
    size_t off = 0;
    auto alloc = [&](size_t bytes) -> void* {
        void* p = ws + off;
        off += (bytes + 255) & ~(size_t)255;
        return p;
    };
    unsigned short* hbuf = (unsigned short*)alloc((size_t)NN * DP * 2);   // h0 / u2
    unsigned short* agg  = (unsigned short*)alloc((size_t)NN * DP * 2);
    unsigned short* u1   = (unsigned short*)alloc((size_t)NN * D2P * 2);
    unsigned short* W1t  = (unsigned short*)alloc((size_t)NL * D2P * DP * 2);
    unsigned short* W2t  = (unsigned short*)alloc((size_t)NL * DP * D2P * 2);
    unsigned short* eec  = (unsigned short*)alloc((size_t)NL * 15 * DP * 2);
    int* row_ptr = (int*)alloc((size_t)(NN + 1) * 4);
    int* cursor  = (int*)alloc((size_t)NN * 4);
    int* counts  = (int*)alloc((size_t)NN * 4);
    int* srcs    = (int*)alloc((size_t)NE * 4);
    int* combos  = (int*)alloc((size_t)NE * 4);
    int* partial  = (int*)alloc(512 * 4);
    int* partial2 = (int*)alloc(512 * 4);
    float* stats1 = (float*)alloc(2 * D2P * 4);
    float* stats2 = (float*)alloc(2 * DP * 4);
    float* sc1 = (float*)alloc(D2P * 4);
    float* sh1 = (float*)alloc(D2P * 4);
    float* sc2 = (float*)alloc(DP * 4);
    float* sh2 = (float*)alloc(DP * 4);
    float* sc0 = (float*)alloc(DP * 4);
    float* sh0 = (float*)alloc(DP * 4);

    // prep
    k_w1t<<<NL * D2P * DP / 256, 256, 0, stream>>>(W1, W1t);
    k_w2t<<<NL * DP * D2P / 256, 256, 0, stream>>>(W2, W2t);
    k_eec<<<(NL * 15 * DP + 255) / 256, 256, 0, stream>>>(ee1, ee2, eec);
    k_h0<<<NN * DP / 256, 256, 0, stream>>>(x, xe1, xe2, hbuf);
    k_ident<<<2, 256, 0, stream>>>(sc0, sh0);

    // CSR
    hipMemsetAsync(counts, 0, (size_t)NN * 4, stream);
    k_count<<<NE / 256, 256, 0, stream>>>(ei, counts);
    k_scan1<<<NN / 256, 256, 0, stream>>>(counts, partial);
    k_scan2<<<1, 512, 0, stream>>>(partial, partial2);
    k_scan3<<<NN / 256, 256, 0, stream>>>(counts, partial2, row_ptr, cursor);
    k_fill<<<NE / 256, 256, 0, stream>>>(ei, ea, cursor, srcs, combos);

    const unsigned short* hcur = hbuf;
    const float* scIn = sc0;
    const float* shIn = sh0;
    int reluIn = 0;
    for (int l = 0; l < NL; ++l) {
        k_gather<<<NN * 40 / 256, 256, 0, stream>>>(hcur, scIn, shIn, reluIn, row_ptr, srcs,
                                                    combos, eec + (size_t)l * 15 * DP, agg);
        hipMemsetAsync(stats1, 0, 2 * D2P * 4, stream);
        dim3 g1(D2P / 64, NN / 128);
        k_gemm<<<g1, 256, 0, stream>>>(agg, DP, DP / 64, nullptr, nullptr, 0,
                                       W1t + (size_t)l * D2P * DP, u1, D2P, stats1, D2P);
        k_bnprep<<<(D2P + 255) / 256, 256, 0, stream>>>(stats1, D2P, D2, bn1g + (size_t)l * D2,
                                                        bn1b + (size_t)l * D2, sc1, sh1);
        hipMemsetAsync(stats2, 0, 2 * DP * 4, stream);
        dim3 g2(DP / 64, NN / 128);
        k_gemm<<<g2, 256, 0, stream>>>(u1, D2P, D2P / 64, sc1, sh1, 1,
                                       W2t + (size_t)l * DP * D2P, hbuf, DP, stats2, DP);
        k_bnprep<<<(DP + 255) / 256, 256, 0, stream>>>(stats2, DP, DD, bng + (size_t)l * DD,
                                                       bnb + (size_t)l * DD, sc2, sh2);
        hcur = hbuf;
        scIn = sc2;
        shIn = sh2;
        reluIn = 1;
    }
    k_out<<<(unsigned int)NN * DD / 256, 256, 0, stream>>>(hbuf, sc2, sh2, out);
}

// Round 3
// 1899.322 us; speedup vs baseline: 1.1561x; 1.1561x over previous
//
#include <hip/hip_runtime.h>
#include <hip/hip_bf16.h>
#include <stdint.h>

#define NN 131072
#define NE 262144
#define DD 300
#define DP 320
#define D2 600
#define D2P 640
#define NL 5
#define BN_EPS 1e-5f

typedef __attribute__((ext_vector_type(8))) _Float16 f16x8;
typedef __attribute__((ext_vector_type(4))) float f32x4;
typedef __attribute__((ext_vector_type(4))) unsigned int uint4v;

static __device__ __forceinline__ float h2f(unsigned short u) {
    union { unsigned short u; _Float16 h; } c; c.u = u; return (float)c.h;
}
static __device__ __forceinline__ unsigned short f2h(float f) {
    union { unsigned short u; _Float16 h; } c; c.h = (_Float16)f; return c.u;
}

// ---------------- prep kernels ----------------

// W1 [L,300,600] fp32 -> W1t [L][640][320] f16 (n-major, k-contig, zero pad)
__global__ void k_w1t(const float* __restrict__ W1, unsigned short* __restrict__ W1t) {
    int idx = blockIdx.x * 256 + threadIdx.x;
    if (idx >= NL * D2P * DP) return;
    int l = idx / (D2P * DP);
    int r = idx % (D2P * DP);
    int n = r / DP, k = r % DP;
    float v = (n < D2 && k < DD) ? W1[(size_t)(l * DD + k) * D2 + n] : 0.f;
    W1t[idx] = f2h(v);
}

// W2 [L,600,300] fp32 -> W2t [L][320][640] f16
__global__ void k_w2t(const float* __restrict__ W2, unsigned short* __restrict__ W2t) {
    int idx = blockIdx.x * 256 + threadIdx.x;
    if (idx >= NL * DP * D2P) return;
    int l = idx / (DP * D2P);
    int r = idx % (DP * D2P);
    int n = r / D2P, k = r % D2P;
    float v = (n < DD && k < D2) ? W2[(size_t)(l * D2 + k) * DD + n] : 0.f;
    W2t[idx] = f2h(v);
}

// edge-embedding combos: eec [L][15][320] f16; combo = bond*3 + dir
__global__ void k_eec(const float* __restrict__ ee1, const float* __restrict__ ee2,
                      unsigned short* __restrict__ eec) {
    int idx = blockIdx.x * 256 + threadIdx.x;
    if (idx >= NL * 15 * DP) return;
    int l = idx / (15 * DP);
    int r = idx % (15 * DP);
    int cb = r / DP, c = r % DP;
    int b = cb / 3, d = cb % 3;
    float v = 0.f;
    if (c < DD) v = ee1[(size_t)(l * 5 + b) * DD + c] + ee2[(size_t)(l * 3 + d) * DD + c];
    eec[idx] = f2h(v);
}

// h0[n][c] = x_emb1[x[n,0]][c] + x_emb2[x[n,1]][c], f16 padded [N][320]
__global__ void k_h0(const int* __restrict__ x, const float* __restrict__ xe1,
                     const float* __restrict__ xe2, unsigned short* __restrict__ h) {
    unsigned int idx = blockIdx.x * 256u + threadIdx.x;
    if (idx >= (unsigned int)NN * DP) return;
    unsigned int n = idx / DP, c = idx % DP;
    float v = 0.f;
    if (c < DD) v = xe1[(size_t)x[2 * n] * DD + c] + xe2[(size_t)x[2 * n + 1] * DD + c];
    h[idx] = f2h(v);
}

__global__ void k_ident(float* __restrict__ sc, float* __restrict__ sh) {
    int t = blockIdx.x * 256 + threadIdx.x;
    if (t < DP) { sc[t] = 1.f; sh[t] = 0.f; }
}

// ---------------- CSR build ----------------

__global__ void k_count(const int* __restrict__ ei, int* __restrict__ counts) {
    int e = blockIdx.x * 256 + threadIdx.x;
    if (e < NE) atomicAdd(&counts[ei[NE + e]], 1);
}

__global__ void k_scan1(const int* __restrict__ counts, int* __restrict__ partial) {
    __shared__ int sm[256];
    int t = threadIdx.x;
    sm[t] = counts[blockIdx.x * 256 + t];
    __syncthreads();
    for (int o = 128; o > 0; o >>= 1) {
        if (t < o) sm[t] += sm[t + o];
        __syncthreads();
    }
    if (t == 0) partial[blockIdx.x] = sm[0];
}

__global__ void k_scan2(const int* __restrict__ partial, int* __restrict__ partial2) {
    __shared__ int sm[512];
    int t = threadIdx.x;
    int v = partial[t];
    sm[t] = v;
    __syncthreads();
    for (int o = 1; o < 512; o <<= 1) {
        int add = (t >= o) ? sm[t - o] : 0;
        __syncthreads();
        sm[t] += add;
        __syncthreads();
    }
    partial2[t] = sm[t] - v;  // exclusive
}

__global__ void k_scan3(const int* __restrict__ counts, const int* __restrict__ partial2,
                        int* __restrict__ row_ptr, int* __restrict__ cursor) {
    __shared__ int sm[256];
    int t = threadIdx.x;
    int i = blockIdx.x * 256 + t;
    int v = counts[i];
    sm[t] = v;
    __syncthreads();
    for (int o = 1; o < 256; o <<= 1) {
        int add = (t >= o) ? sm[t - o] : 0;
        __syncthreads();
        sm[t] += add;
        __syncthreads();
    }
    int excl = partial2[blockIdx.x] + sm[t] - v;
    row_ptr[i] = excl;
    cursor[i] = excl;
    if (i == NN - 1) row_ptr[NN] = excl + v;
}

__global__ void k_fill(const int* __restrict__ ei, const int* __restrict__ ea,
                       int* __restrict__ cursor, int* __restrict__ srcs,
                       int* __restrict__ combos) {
    int e = blockIdx.x * 256 + threadIdx.x;
    if (e >= NE) return;
    int d = ei[NE + e];
    int pos = atomicAdd(&cursor[d], 1);
    srcs[pos] = ei[e];
    combos[pos] = ea[2 * e] * 3 + ea[2 * e + 1];
}

// ---------------- aggregation (pull, CSR) ----------------
__global__ void k_gather(const unsigned short* __restrict__ h, const float* __restrict__ sc,
                         const float* __restrict__ sh, int relu,
                         const int* __restrict__ row_ptr, const int* __restrict__ srcs,
                         const int* __restrict__ combos, const unsigned short* __restrict__ eec,
                         unsigned short* __restrict__ agg) {
    unsigned int idx = blockIdx.x * 256u + threadIdx.x;  // N*40 chunks of 8 cols
    if (idx >= (unsigned int)NN * 40) return;
    unsigned int m = idx / 40;
    unsigned int j = idx % 40;
    int c0 = j * 8;
    float a[8] = {0, 0, 0, 0, 0, 0, 0, 0};
    float scv[8], shv[8];
#pragma unroll
    for (int i = 0; i < 8; i++) { scv[i] = sc[c0 + i]; shv[i] = sh[c0 + i]; }
    int e0 = row_ptr[m], e1 = row_ptr[m + 1];
    for (int e = e0; e < e1; ++e) {
        int s = srcs[e], cb = combos[e];
        uint4v hv = *(const uint4v*)(h + (size_t)s * DP + c0);
        uint4v ev = *(const uint4v*)(eec + (size_t)cb * DP + c0);
        const unsigned short* hp = (const unsigned short*)&hv;
        const unsigned short* ep = (const unsigned short*)&ev;
#pragma unroll
        for (int i = 0; i < 8; i++) {
            float f = scv[i] * h2f(hp[i]) + shv[i];
            if (relu) f = fmaxf(f, 0.f);
            a[i] += f + h2f(ep[i]);
        }
    }
    unsigned short o[8];
#pragma unroll
    for (int i = 0; i < 8; i++) o[i] = f2h(a[i]);
    *(uint4v*)(agg + (size_t)m * DP + c0) = *(const uint4v*)o;
}

// ---------------- big-N GEMM ----------------
// C[M, n0+0..n0+319] = affine?(A)[M,K] @ B^T, B rows pre-offset by n0.
// grid = (Nout/320, M/128), 512 threads = 8 waves (2m x 4n).
// A reg-staged (optional f16 affine+relu fold), B via global_load_lds,
// both XOR-swizzled (c16 ^= row&7) for conflict-free ds_read_b128.
__launch_bounds__(512, 4)
__global__ void k_gemmN(const unsigned short* __restrict__ A, int lda, int kIters,
                        const unsigned short* __restrict__ scH,
                        const unsigned short* __restrict__ shH,
                        const unsigned short* __restrict__ B,
                        unsigned short* __restrict__ C, int ldc,
                        float* __restrict__ stats, int statN) {
    __shared__ unsigned short As[128 * 64];
    __shared__ unsigned short Bs[320 * 64];
    int tid = threadIdx.x;
    int lane = tid & 63, wid = tid >> 6;
    int wm = wid >> 2, wn = wid & 3;
    int m0 = blockIdx.y * 128;
    int n0 = blockIdx.x * 320;
    const unsigned short* Bb = B + (size_t)n0 * lda;

    // A staging geometry: thread -> (row, two 16B slots)
    int srow = tid >> 2;       // 0..127
    int sc16 = tid & 3;        // slots sc16 and sc16+4
    const unsigned short* aRow = A + (size_t)(m0 + srow) * lda;
    int swz = srow & 7;
    // B staging geometry
    int brow8 = lane >> 3;     // row within 8-row chunk
    int bc16 = (lane & 7) ^ brow8;  // pre-swizzled global slot

    f32x4 acc[4][5] = {};

    for (int kt = 0; kt < kIters; ++kt) {
        int k0 = kt * 64;
        // issue B DMA first (latency overlap)
#pragma unroll
        for (int j = 0; j < 5; ++j) {
            int chunk = wid * 5 + j;
            int n = chunk * 8 + brow8;
            const unsigned short* g = Bb + (size_t)n * lda + k0 + bc16 * 8;
            __builtin_amdgcn_global_load_lds(
                (const __attribute__((address_space(1))) unsigned int*)g,
                (__attribute__((address_space(3))) unsigned int*)&Bs[chunk * 512], 16, 0, 0);
        }
        // A: global -> reg -> (affine) -> swizzled LDS
        uint4v v0 = *(const uint4v*)(aRow + k0 + sc16 * 8);
        uint4v v1 = *(const uint4v*)(aRow + k0 + (sc16 + 4) * 8);
        if (scH) {
            f16x8 a0 = *(f16x8*)&v0, a1 = *(f16x8*)&v1;
            f16x8 s0 = *(const f16x8*)&scH[k0 + sc16 * 8];
            f16x8 h0 = *(const f16x8*)&shH[k0 + sc16 * 8];
            f16x8 s1 = *(const f16x8*)&scH[k0 + (sc16 + 4) * 8];
            f16x8 h1 = *(const f16x8*)&shH[k0 + (sc16 + 4) * 8];
#pragma unroll
            for (int i = 0; i < 8; i++) {
                _Float16 t0 = a0[i] * s0[i] + h0[i];
                _Float16 t1 = a1[i] * s1[i] + h1[i];
                a0[i] = t0 > (_Float16)0 ? t0 : (_Float16)0;
                a1[i] = t1 > (_Float16)0 ? t1 : (_Float16)0;
            }
            v0 = *(uint4v*)&a0;
            v1 = *(uint4v*)&a1;
        }
        *(uint4v*)&As[srow * 64 + ((sc16 ^ swz) * 8)] = v0;
        *(uint4v*)&As[srow * 64 + (((sc16 + 4) ^ swz) * 8)] = v1;
        __syncthreads();
#pragma unroll
        for (int ks = 0; ks < 2; ++ks) {
            f16x8 af[4];
#pragma unroll
            for (int mf = 0; mf < 4; ++mf) {
                int ra = wm * 64 + mf * 16 + (lane & 15);
                int c16 = (ks * 4 + (lane >> 4)) ^ (ra & 7);
                af[mf] = *(const f16x8*)&As[ra * 64 + c16 * 8];
            }
#pragma unroll
            for (int nf = 0; nf < 5; ++nf) {
                int rb = wn * 80 + nf * 16 + (lane & 15);
                int c16 = (ks * 4 + (lane >> 4)) ^ (rb & 7);
                f16x8 bg = *(const f16x8*)&Bs[rb * 64 + c16 * 8];
#pragma unroll
                for (int mf = 0; mf < 4; ++mf)
                    acc[mf][nf] = __builtin_amdgcn_mfma_f32_16x16x32_f16(af[mf], bg, acc[mf][nf], 0, 0, 0);
            }
        }
        __syncthreads();
    }
    // epilogue: store C (f16) + per-column stats
#pragma unroll
    for (int nf = 0; nf < 5; ++nf) {
        int col = n0 + wn * 80 + nf * 16 + (lane & 15);
        float s = 0.f, ss = 0.f;
#pragma unroll
        for (int mf = 0; mf < 4; ++mf) {
            int rbase = m0 + wm * 64 + mf * 16 + ((lane >> 4) << 2);
#pragma unroll
            for (int i = 0; i < 4; ++i) {
                float v = acc[mf][nf][i];
                unsigned short hb = f2h(v);
                C[(size_t)(rbase + i) * ldc + col] = hb;
                float vr = h2f(hb);
                s += vr;
                ss += vr * vr;
            }
        }
        s += __shfl_xor(s, 16); s += __shfl_xor(s, 32);
        ss += __shfl_xor(ss, 16); ss += __shfl_xor(ss, 32);
        if (lane < 16) {
            atomicAdd(&stats[col], s);
            atomicAdd(&stats[statN + col], ss);
        }
    }
}

// ---------------- BN scale/shift from stats (f32 + f16 copies) ----------------
__global__ void k_bnprep(const float* __restrict__ stats, int statN, int realN,
                         const float* __restrict__ g, const float* __restrict__ b,
                         float* __restrict__ sc, float* __restrict__ sh,
                         unsigned short* __restrict__ scH, unsigned short* __restrict__ shH) {
    int n = blockIdx.x * 256 + threadIdx.x;
    if (n >= statN) return;
    float scv = 0.f, shv = 0.f;
    if (n < realN) {
        float mu = stats[n] * (1.f / NN);
        float var = stats[statN + n] * (1.f / NN) - mu * mu;
        var = fmaxf(var, 0.f);
        float rs = rsqrtf(var + BN_EPS);
        scv = g[n] * rs;
        shv = b[n] - mu * scv;
    }
    sc[n] = scv;
    sh[n] = shv;
    scH[n] = f2h(scv);
    shH[n] = f2h(shv);
}

// ---------------- final output ----------------
__global__ void k_out(const unsigned short* __restrict__ u2, const float* __restrict__ sc,
                      const float* __restrict__ sh, float* __restrict__ out) {
    unsigned int idx = blockIdx.x * 256u + threadIdx.x;
    if (idx >= (unsigned int)NN * DD) return;
    unsigned int n = idx / DD, d = idx % DD;
    out[idx] = sc[d] * h2f(u2[(size_t)n * DP + d]) + sh[d];
}

extern "C" void kernel_launch(void* const* d_in, const int* in_sizes, int n_in,
                              void* d_out, int out_size, void* d_ws, size_t ws_size,
                              hipStream_t stream) {
    const int* x = (const int*)d_in[0];
    const int* ei = (const int*)d_in[1];
    const int* ea = (const int*)d_in[2];
    const float* xe1 = (const float*)d_in[3];
    const float* xe2 = (const float*)d_in[4];
    const float* ee1 = (const float*)d_in[5];
    const float* ee2 = (const float*)d_in[6];
    const float* W1 = (const float*)d_in[7];
    const float* bn1g = (const float*)d_in[9];
    const float* bn1b = (const float*)d_in[10];
    const float* W2 = (const float*)d_in[11];
    const float* bng = (const float*)d_in[13];
    const float* bnb = (const float*)d_in[14];
    float* out = (float*)d_out;

    char* ws = (char*)d_ws;
    size_t off = 0;
    auto alloc = [&](size_t bytes) -> void* {
        void* p = ws + off;
        off += (bytes + 255) & ~(size_t)255;
        return p;
    };
    unsigned short* hbuf = (unsigned short*)alloc((size_t)NN * DP * 2);   // h0 / u2
    unsigned short* agg  = (unsigned short*)alloc((size_t)NN * DP * 2);
    unsigned short* u1   = (unsigned short*)alloc((size_t)NN * D2P * 2);
    unsigned short* W1t  = (unsigned short*)alloc((size_t)NL * D2P * DP * 2);
    unsigned short* W2t  = (unsigned short*)alloc((size_t)NL * DP * D2P * 2);
    unsigned short* eec  = (unsigned short*)alloc((size_t)NL * 15 * DP * 2);
    int* row_ptr = (int*)alloc((size_t)(NN + 1) * 4);
    int* cursor  = (int*)alloc((size_t)NN * 4);
    int* counts  = (int*)alloc((size_t)NN * 4);
    int* srcs    = (int*)alloc((size_t)NE * 4);
    int* combos  = (int*)alloc((size_t)NE * 4);
    int* partial  = (int*)alloc(512 * 4);
    int* partial2 = (int*)alloc(512 * 4);
    float* stats1 = (float*)alloc(2 * D2P * 4);
    float* stats2 = (float*)alloc(2 * DP * 4);
    float* sc1 = (float*)alloc(D2P * 4);
    float* sh1 = (float*)alloc(D2P * 4);
    float* sc2 = (float*)alloc(DP * 4);
    float* sh2 = (float*)alloc(DP * 4);
    float* sc0 = (float*)alloc(DP * 4);
    float* sh0 = (float*)alloc(DP * 4);
    unsigned short* scH1 = (unsigned short*)alloc(D2P * 2);
    unsigned short* shH1 = (unsigned short*)alloc(D2P * 2);
    unsigned short* scH2 = (unsigned short*)alloc(DP * 2);
    unsigned short* shH2 = (unsigned short*)alloc(DP * 2);

    // prep
    k_w1t<<<NL * D2P * DP / 256, 256, 0, stream>>>(W1, W1t);
    k_w2t<<<NL * DP * D2P / 256, 256, 0, stream>>>(W2, W2t);
    k_eec<<<(NL * 15 * DP + 255) / 256, 256, 0, stream>>>(ee1, ee2, eec);
    k_h0<<<NN * DP / 256, 256, 0, stream>>>(x, xe1, xe2, hbuf);
    k_ident<<<2, 256, 0, stream>>>(sc0, sh0);

    // CSR
    hipMemsetAsync(counts, 0, (size_t)NN * 4, stream);
    k_count<<<NE / 256, 256, 0, stream>>>(ei, counts);
    k_scan1<<<NN / 256, 256, 0, stream>>>(counts, partial);
    k_scan2<<<1, 512, 0, stream>>>(partial, partial2);
    k_scan3<<<NN / 256, 256, 0, stream>>>(counts, partial2, row_ptr, cursor);
    k_fill<<<NE / 256, 256, 0, stream>>>(ei, ea, cursor, srcs, combos);

    const unsigned short* hcur = hbuf;
    const float* scIn = sc0;
    const float* shIn = sh0;
    int reluIn = 0;
    for (int l = 0; l < NL; ++l) {
        k_gather<<<NN * 40 / 256, 256, 0, stream>>>(hcur, scIn, shIn, reluIn, row_ptr, srcs,
                                                    combos, eec + (size_t)l * 15 * DP, agg);
        hipMemsetAsync(stats1, 0, 2 * D2P * 4, stream);
        dim3 g1(D2P / 320, NN / 128);
        k_gemmN<<<g1, 512, 0, stream>>>(agg, DP, DP / 64, nullptr, nullptr,
                                        W1t + (size_t)l * D2P * DP, u1, D2P, stats1, D2P);
        k_bnprep<<<(D2P + 255) / 256, 256, 0, stream>>>(stats1, D2P, D2, bn1g + (size_t)l * D2,
                                                        bn1b + (size_t)l * D2, sc1, sh1, scH1, shH1);
        hipMemsetAsync(stats2, 0, 2 * DP * 4, stream);
        dim3 g2(DP / 320, NN / 128);
        k_gemmN<<<g2, 512, 0, stream>>>(u1, D2P, D2P / 64, scH1, shH1,
                                        W2t + (size_t)l * DP * D2P, hbuf, DP, stats2, DP);
        k_bnprep<<<(DP + 255) / 256, 256, 0, stream>>>(stats2, DP, DD, bng + (size_t)l * DD,
                                                       bnb + (size_t)l * DD, sc2, sh2, scH2, shH2);
        hcur = hbuf;
        scIn = sc2;
        shIn = sh2;
        reluIn = 1;
    }
    k_out<<<(unsigned int)NN * DD / 256, 256, 0, stream>>>(hbuf, sc2, sh2, out);
}

// Round 4
// 1839.034 us; speedup vs baseline: 1.1940x; 1.0328x over previous
//
#include <hip/hip_runtime.h>
#include <hip/hip_bf16.h>
#include <stdint.h>

#define NN 131072
#define NE 262144
#define DD 300
#define DP 320
#define D2 600
#define D2P 640
#define NL 5
#define BN_EPS 1e-5f

typedef __attribute__((ext_vector_type(8))) _Float16 f16x8;
typedef __attribute__((ext_vector_type(4))) float f32x4;
typedef __attribute__((ext_vector_type(4))) unsigned int uint4v;

static __device__ __forceinline__ float h2f(unsigned short u) {
    union { unsigned short u; _Float16 h; } c; c.u = u; return (float)c.h;
}
static __device__ __forceinline__ unsigned short f2h(float f) {
    union { unsigned short u; _Float16 h; } c; c.h = (_Float16)f; return c.u;
}

// ---------------- prep kernels ----------------

// W1 [L,300,600] fp32 -> W1t [L][640][320] f16 (n-major, k-contig, zero pad)
__global__ void k_w1t(const float* __restrict__ W1, unsigned short* __restrict__ W1t) {
    int idx = blockIdx.x * 256 + threadIdx.x;
    if (idx >= NL * D2P * DP) return;
    int l = idx / (D2P * DP);
    int r = idx % (D2P * DP);
    int n = r / DP, k = r % DP;
    float v = (n < D2 && k < DD) ? W1[(size_t)(l * DD + k) * D2 + n] : 0.f;
    W1t[idx] = f2h(v);
}

// W2 [L,600,300] fp32 -> W2t [L][320][640] f16
__global__ void k_w2t(const float* __restrict__ W2, unsigned short* __restrict__ W2t) {
    int idx = blockIdx.x * 256 + threadIdx.x;
    if (idx >= NL * DP * D2P) return;
    int l = idx / (DP * D2P);
    int r = idx % (DP * D2P);
    int n = r / D2P, k = r % D2P;
    float v = (n < DD && k < D2) ? W2[(size_t)(l * D2 + k) * DD + n] : 0.f;
    W2t[idx] = f2h(v);
}

// edge-embedding combos: eec [L][15][320] f16; combo = bond*3 + dir
__global__ void k_eec(const float* __restrict__ ee1, const float* __restrict__ ee2,
                      unsigned short* __restrict__ eec) {
    int idx = blockIdx.x * 256 + threadIdx.x;
    if (idx >= NL * 15 * DP) return;
    int l = idx / (15 * DP);
    int r = idx % (15 * DP);
    int cb = r / DP, c = r % DP;
    int b = cb / 3, d = cb % 3;
    float v = 0.f;
    if (c < DD) v = ee1[(size_t)(l * 5 + b) * DD + c] + ee2[(size_t)(l * 3 + d) * DD + c];
    eec[idx] = f2h(v);
}

// h0[n][c] = x_emb1[x[n,0]][c] + x_emb2[x[n,1]][c], f16 padded [N][320]
__global__ void k_h0(const int* __restrict__ x, const float* __restrict__ xe1,
                     const float* __restrict__ xe2, unsigned short* __restrict__ h) {
    unsigned int idx = blockIdx.x * 256u + threadIdx.x;
    if (idx >= (unsigned int)NN * DP) return;
    unsigned int n = idx / DP, c = idx % DP;
    float v = 0.f;
    if (c < DD) v = xe1[(size_t)x[2 * n] * DD + c] + xe2[(size_t)x[2 * n + 1] * DD + c];
    h[idx] = f2h(v);
}

__global__ void k_ident(float* __restrict__ sc, float* __restrict__ sh) {
    int t = blockIdx.x * 256 + threadIdx.x;
    if (t < DP) { sc[t] = 1.f; sh[t] = 0.f; }
}

// ---------------- CSR build ----------------

__global__ void k_count(const int* __restrict__ ei, int* __restrict__ counts) {
    int e = blockIdx.x * 256 + threadIdx.x;
    if (e < NE) atomicAdd(&counts[ei[NE + e]], 1);
}

__global__ void k_scan1(const int* __restrict__ counts, int* __restrict__ partial) {
    __shared__ int sm[256];
    int t = threadIdx.x;
    sm[t] = counts[blockIdx.x * 256 + t];
    __syncthreads();
    for (int o = 128; o > 0; o >>= 1) {
        if (t < o) sm[t] += sm[t + o];
        __syncthreads();
    }
    if (t == 0) partial[blockIdx.x] = sm[0];
}

__global__ void k_scan2(const int* __restrict__ partial, int* __restrict__ partial2) {
    __shared__ int sm[512];
    int t = threadIdx.x;
    int v = partial[t];
    sm[t] = v;
    __syncthreads();
    for (int o = 1; o < 512; o <<= 1) {
        int add = (t >= o) ? sm[t - o] : 0;
        __syncthreads();
        sm[t] += add;
        __syncthreads();
    }
    partial2[t] = sm[t] - v;  // exclusive
}

__global__ void k_scan3(const int* __restrict__ counts, const int* __restrict__ partial2,
                        int* __restrict__ row_ptr, int* __restrict__ cursor) {
    __shared__ int sm[256];
    int t = threadIdx.x;
    int i = blockIdx.x * 256 + t;
    int v = counts[i];
    sm[t] = v;
    __syncthreads();
    for (int o = 1; o < 256; o <<= 1) {
        int add = (t >= o) ? sm[t - o] : 0;
        __syncthreads();
        sm[t] += add;
        __syncthreads();
    }
    int excl = partial2[blockIdx.x] + sm[t] - v;
    row_ptr[i] = excl;
    cursor[i] = excl;
    if (i == NN - 1) row_ptr[NN] = excl + v;
}

__global__ void k_fill(const int* __restrict__ ei, const int* __restrict__ ea,
                       int* __restrict__ cursor, int* __restrict__ srcs,
                       int* __restrict__ combos) {
    int e = blockIdx.x * 256 + threadIdx.x;
    if (e >= NE) return;
    int d = ei[NE + e];
    int pos = atomicAdd(&cursor[d], 1);
    srcs[pos] = ei[e];
    combos[pos] = ea[2 * e] * 3 + ea[2 * e + 1];
}

// ---------------- aggregation (pull, CSR) ----------------
__global__ void k_gather(const unsigned short* __restrict__ h, const float* __restrict__ sc,
                         const float* __restrict__ sh, int relu,
                         const int* __restrict__ row_ptr, const int* __restrict__ srcs,
                         const int* __restrict__ combos, const unsigned short* __restrict__ eec,
                         unsigned short* __restrict__ agg) {
    unsigned int idx = blockIdx.x * 256u + threadIdx.x;  // N*40 chunks of 8 cols
    if (idx >= (unsigned int)NN * 40) return;
    unsigned int m = idx / 40;
    unsigned int j = idx % 40;
    int c0 = j * 8;
    float a[8] = {0, 0, 0, 0, 0, 0, 0, 0};
    float scv[8], shv[8];
#pragma unroll
    for (int i = 0; i < 8; i++) { scv[i] = sc[c0 + i]; shv[i] = sh[c0 + i]; }
    int e0 = row_ptr[m], e1 = row_ptr[m + 1];
    for (int e = e0; e < e1; ++e) {
        int s = srcs[e], cb = combos[e];
        uint4v hv = *(const uint4v*)(h + (size_t)s * DP + c0);
        uint4v ev = *(const uint4v*)(eec + (size_t)cb * DP + c0);
        const unsigned short* hp = (const unsigned short*)&hv;
        const unsigned short* ep = (const unsigned short*)&ev;
#pragma unroll
        for (int i = 0; i < 8; i++) {
            float f = scv[i] * h2f(hp[i]) + shv[i];
            if (relu) f = fmaxf(f, 0.f);
            a[i] += f + h2f(ep[i]);
        }
    }
    unsigned short o[8];
#pragma unroll
    for (int i = 0; i < 8; i++) o[i] = f2h(a[i]);
    *(uint4v*)(agg + (size_t)m * DP + c0) = *(const uint4v*)o;
}

// ---------------- big-N GEMM ----------------
// C[M, n0..n0+319] = affine?(A)[M,K] @ B^T, grid (Nout/320, M/128), 512 thr, 8 waves (2m x 4n).
// A reg-staged (optional f16 affine+relu fold), B via global_load_lds, XOR-swizzled LDS.
// Epilogue: LDS-transpose -> coalesced dwordx4 row stores (write inflation fix).
#define TLD 328  // transpose-tile row stride (f16 elems); 656B rotates banks by 4/row
__launch_bounds__(512, 2)
__global__ void k_gemmN(const unsigned short* __restrict__ A, int lda, int kIters,
                        const unsigned short* __restrict__ scH,
                        const unsigned short* __restrict__ shH,
                        const unsigned short* __restrict__ B,
                        unsigned short* __restrict__ C, int ldc,
                        float* __restrict__ stats, int statN) {
    __shared__ unsigned short smem[128 * 64 + 320 * 64];  // As | Bs ; reused as T[64][328]
    unsigned short* As = smem;
    unsigned short* Bs = smem + 128 * 64;
    int tid = threadIdx.x;
    int lane = tid & 63, wid = tid >> 6;
    int wm = wid >> 2, wn = wid & 3;
    int m0 = blockIdx.y * 128;
    int n0 = blockIdx.x * 320;
    const unsigned short* Bb = B + (size_t)n0 * lda;

    // A staging geometry: thread -> (row, two 16B slots)
    int srow = tid >> 2;       // 0..127
    int sc16 = tid & 3;        // slots sc16 and sc16+4
    const unsigned short* aRow = A + (size_t)(m0 + srow) * lda;
    int swz = srow & 7;
    // B staging geometry
    int brow8 = lane >> 3;          // row within 8-row chunk
    int bc16 = (lane & 7) ^ brow8;  // pre-swizzled global slot

    f32x4 acc[4][5] = {};

    for (int kt = 0; kt < kIters; ++kt) {
        int k0 = kt * 64;
        // issue B DMA first (latency overlap)
#pragma unroll
        for (int j = 0; j < 5; ++j) {
            int chunk = wid * 5 + j;
            int n = chunk * 8 + brow8;
            const unsigned short* g = Bb + (size_t)n * lda + k0 + bc16 * 8;
            __builtin_amdgcn_global_load_lds(
                (const __attribute__((address_space(1))) unsigned int*)g,
                (__attribute__((address_space(3))) unsigned int*)&Bs[chunk * 512], 16, 0, 0);
        }
        // A: global -> reg -> (affine) -> swizzled LDS
        uint4v v0 = *(const uint4v*)(aRow + k0 + sc16 * 8);
        uint4v v1 = *(const uint4v*)(aRow + k0 + (sc16 + 4) * 8);
        if (scH) {
            f16x8 a0 = *(f16x8*)&v0, a1 = *(f16x8*)&v1;
            f16x8 s0 = *(const f16x8*)&scH[k0 + sc16 * 8];
            f16x8 h0 = *(const f16x8*)&shH[k0 + sc16 * 8];
            f16x8 s1 = *(const f16x8*)&scH[k0 + (sc16 + 4) * 8];
            f16x8 h1 = *(const f16x8*)&shH[k0 + (sc16 + 4) * 8];
#pragma unroll
            for (int i = 0; i < 8; i++) {
                _Float16 t0 = a0[i] * s0[i] + h0[i];
                _Float16 t1 = a1[i] * s1[i] + h1[i];
                a0[i] = t0 > (_Float16)0 ? t0 : (_Float16)0;
                a1[i] = t1 > (_Float16)0 ? t1 : (_Float16)0;
            }
            v0 = *(uint4v*)&a0;
            v1 = *(uint4v*)&a1;
        }
        *(uint4v*)&As[srow * 64 + ((sc16 ^ swz) * 8)] = v0;
        *(uint4v*)&As[srow * 64 + (((sc16 + 4) ^ swz) * 8)] = v1;
        __syncthreads();
#pragma unroll
        for (int ks = 0; ks < 2; ++ks) {
            f16x8 af[4];
#pragma unroll
            for (int mf = 0; mf < 4; ++mf) {
                int ra = wm * 64 + mf * 16 + (lane & 15);
                int c16 = (ks * 4 + (lane >> 4)) ^ (ra & 7);
                af[mf] = *(const f16x8*)&As[ra * 64 + c16 * 8];
            }
#pragma unroll
            for (int nf = 0; nf < 5; ++nf) {
                int rb = wn * 80 + nf * 16 + (lane & 15);
                int c16 = (ks * 4 + (lane >> 4)) ^ (rb & 7);
                f16x8 bg = *(const f16x8*)&Bs[rb * 64 + c16 * 8];
#pragma unroll
                for (int mf = 0; mf < 4; ++mf)
                    acc[mf][nf] = __builtin_amdgcn_mfma_f32_16x16x32_f16(af[mf], bg, acc[mf][nf], 0, 0, 0);
            }
        }
        __syncthreads();
    }

    // ---- per-column stats (on f16-rounded values, matching stored C) ----
#pragma unroll
    for (int nf = 0; nf < 5; ++nf) {
        int col = n0 + wn * 80 + nf * 16 + (lane & 15);
        float s = 0.f, ss = 0.f;
#pragma unroll
        for (int mf = 0; mf < 4; ++mf) {
#pragma unroll
            for (int i = 0; i < 4; ++i) {
                float vr = h2f(f2h(acc[mf][nf][i]));
                s += vr;
                ss += vr * vr;
            }
        }
        s += __shfl_xor(s, 16); s += __shfl_xor(s, 32);
        ss += __shfl_xor(ss, 16); ss += __shfl_xor(ss, 32);
        if (lane < 16) {
            atomicAdd(&stats[col], s);
            atomicAdd(&stats[statN + col], ss);
        }
    }

    // ---- LDS-transpose epilogue: coalesced row-major stores ----
    unsigned short* T = smem;  // 64 x TLD f16 = 41 KB, fits in As|Bs region
#pragma unroll
    for (int half = 0; half < 2; ++half) {
        __syncthreads();
        if (wm == half) {
#pragma unroll
            for (int nf = 0; nf < 5; ++nf) {
                int col = wn * 80 + nf * 16 + (lane & 15);
#pragma unroll
                for (int mf = 0; mf < 4; ++mf) {
                    int r = mf * 16 + ((lane >> 4) << 2);
#pragma unroll
                    for (int i = 0; i < 4; ++i)
                        T[(r + i) * TLD + col] = f2h(acc[mf][nf][i]);
                }
            }
        }
        __syncthreads();
        int rowbase = m0 + half * 64;
#pragma unroll
        for (int p = 0; p < 5; ++p) {
            int cid = p * 512 + tid;          // 0..2559
            int r = cid / 40, c16 = cid % 40;
            uint4v v = *(const uint4v*)&T[r * TLD + c16 * 8];
            *(uint4v*)&C[(size_t)(rowbase + r) * ldc + n0 + c16 * 8] = v;
        }
    }
}

// ---------------- BN scale/shift from stats (f32 + f16 copies) ----------------
__global__ void k_bnprep(const float* __restrict__ stats, int statN, int realN,
                         const float* __restrict__ g, const float* __restrict__ b,
                         float* __restrict__ sc, float* __restrict__ sh,
                         unsigned short* __restrict__ scH, unsigned short* __restrict__ shH) {
    int n = blockIdx.x * 256 + threadIdx.x;
    if (n >= statN) return;
    float scv = 0.f, shv = 0.f;
    if (n < realN) {
        float mu = stats[n] * (1.f / NN);
        float var = stats[statN + n] * (1.f / NN) - mu * mu;
        var = fmaxf(var, 0.f);
        float rs = rsqrtf(var + BN_EPS);
        scv = g[n] * rs;
        shv = b[n] - mu * scv;
    }
    sc[n] = scv;
    sh[n] = shv;
    scH[n] = f2h(scv);
    shH[n] = f2h(shv);
}

// ---------------- final output ----------------
__global__ void k_out(const unsigned short* __restrict__ u2, const float* __restrict__ sc,
                      const float* __restrict__ sh, float* __restrict__ out) {
    unsigned int idx = blockIdx.x * 256u + threadIdx.x;
    if (idx >= (unsigned int)NN * DD) return;
    unsigned int n = idx / DD, d = idx % DD;
    out[idx] = sc[d] * h2f(u2[(size_t)n * DP + d]) + sh[d];
}

extern "C" void kernel_launch(void* const* d_in, const int* in_sizes, int n_in,
                              void* d_out, int out_size, void* d_ws, size_t ws_size,
                              hipStream_t stream) {
    const int* x = (const int*)d_in[0];
    const int* ei = (const int*)d_in[1];
    const int* ea = (const int*)d_in[2];
    const float* xe1 = (const float*)d_in[3];
    const float* xe2 = (const float*)d_in[4];
    const float* ee1 = (const float*)d_in[5];
    const float* ee2 = (const float*)d_in[6];
    const float* W1 = (const float*)d_in[7];
    const float* bn1g = (const float*)d_in[9];
    const float* bn1b = (const float*)d_in[10];
    const float* W2 = (const float*)d_in[11];
    const float* bng = (const float*)d_in[13];
    const float* bnb = (const float*)d_in[14];
    float* out = (float*)d_out;

    char* ws = (char*)d_ws;
    size_t off = 0;
    auto alloc = [&](size_t bytes) -> void* {
        void* p = ws + off;
        off += (bytes + 255) & ~(size_t)255;
        return p;
    };
    unsigned short* hbuf = (unsigned short*)alloc((size_t)NN * DP * 2);   // h0 / u2
    unsigned short* agg  = (unsigned short*)alloc((size_t)NN * DP * 2);
    unsigned short* u1   = (unsigned short*)alloc((size_t)NN * D2P * 2);
    unsigned short* W1t  = (unsigned short*)alloc((size_t)NL * D2P * DP * 2);
    unsigned short* W2t  = (unsigned short*)alloc((size_t)NL * DP * D2P * 2);
    unsigned short* eec  = (unsigned short*)alloc((size_t)NL * 15 * DP * 2);
    int* row_ptr = (int*)alloc((size_t)(NN + 1) * 4);
    int* cursor  = (int*)alloc((size_t)NN * 4);
    int* counts  = (int*)alloc((size_t)NN * 4);
    int* srcs    = (int*)alloc((size_t)NE * 4);
    int* combos  = (int*)alloc((size_t)NE * 4);
    int* partial  = (int*)alloc(512 * 4);
    int* partial2 = (int*)alloc(512 * 4);
    float* stats1 = (float*)alloc(2 * D2P * 4);
    float* stats2 = (float*)alloc(2 * DP * 4);
    float* sc1 = (float*)alloc(D2P * 4);
    float* sh1 = (float*)alloc(D2P * 4);
    float* sc2 = (float*)alloc(DP * 4);
    float* sh2 = (float*)alloc(DP * 4);
    float* sc0 = (float*)alloc(DP * 4);
    float* sh0 = (float*)alloc(DP * 4);
    unsigned short* scH1 = (unsigned short*)alloc(D2P * 2);
    unsigned short* shH1 = (unsigned short*)alloc(D2P * 2);
    unsigned short* scH2 = (unsigned short*)alloc(DP * 2);
    unsigned short* shH2 = (unsigned short*)alloc(DP * 2);

    // prep
    k_w1t<<<NL * D2P * DP / 256, 256, 0, stream>>>(W1, W1t);
    k_w2t<<<NL * DP * D2P / 256, 256, 0, stream>>>(W2, W2t);
    k_eec<<<(NL * 15 * DP + 255) / 256, 256, 0, stream>>>(ee1, ee2, eec);
    k_h0<<<NN * DP / 256, 256, 0, stream>>>(x, xe1, xe2, hbuf);
    k_ident<<<2, 256, 0, stream>>>(sc0, sh0);

    // CSR
    hipMemsetAsync(counts, 0, (size_t)NN * 4, stream);
    k_count<<<NE / 256, 256, 0, stream>>>(ei, counts);
    k_scan1<<<NN / 256, 256, 0, stream>>>(counts, partial);
    k_scan2<<<1, 512, 0, stream>>>(partial, partial2);
    k_scan3<<<NN / 256, 256, 0, stream>>>(counts, partial2, row_ptr, cursor);
    k_fill<<<NE / 256, 256, 0, stream>>>(ei, ea, cursor, srcs, combos);

    const unsigned short* hcur = hbuf;
    const float* scIn = sc0;
    const float* shIn = sh0;
    int reluIn = 0;
    for (int l = 0; l < NL; ++l) {
        k_gather<<<NN * 40 / 256, 256, 0, stream>>>(hcur, scIn, shIn, reluIn, row_ptr, srcs,
                                                    combos, eec + (size_t)l * 15 * DP, agg);
        hipMemsetAsync(stats1, 0, 2 * D2P * 4, stream);
        dim3 g1(D2P / 320, NN / 128);
        k_gemmN<<<g1, 512, 0, stream>>>(agg, DP, DP / 64, nullptr, nullptr,
                                        W1t + (size_t)l * D2P * DP, u1, D2P, stats1, D2P);
        k_bnprep<<<(D2P + 255) / 256, 256, 0, stream>>>(stats1, D2P, D2, bn1g + (size_t)l * D2,
                                                        bn1b + (size_t)l * D2, sc1, sh1, scH1, shH1);
        hipMemsetAsync(stats2, 0, 2 * DP * 4, stream);
        dim3 g2(DP / 320, NN / 128);
        k_gemmN<<<g2, 512, 0, stream>>>(u1, D2P, D2P / 64, scH1, shH1,
                                        W2t + (size_t)l * DP * D2P, hbuf, DP, stats2, DP);
        k_bnprep<<<(DP + 255) / 256, 256, 0, stream>>>(stats2, DP, DD, bng + (size_t)l * DD,
                                                       bnb + (size_t)l * DD, sc2, sh2, scH2, shH2);
        hcur = hbuf;
        scIn = sc2;
        shIn = sh2;
        reluIn = 1;
    }
    k_out<<<(unsigned int)NN * DD / 256, 256, 0, stream>>>(hbuf, sc2, sh2, out);
}